// Round 2
// baseline (251.151 us; speedup 1.0000x reference)
//
#include <hip/hip_runtime.h>

#define D 128
#define HEADS 4

typedef __attribute__((ext_vector_type(8))) short short8;
typedef __attribute__((ext_vector_type(4))) float f32x4;
typedef __attribute__((ext_vector_type(2))) float f32x2;
typedef __attribute__((ext_vector_type(2))) unsigned int u32x2;

static __device__ __forceinline__ float leaky(float v) { return v > 0.f ? v : 0.2f * v; }

static __device__ __forceinline__ f32x2 bf2_to_p2(unsigned int u) {
    union { unsigned int i; float f; } a, b;
    a.i = u << 16;              // low bf16 -> f32
    b.i = u & 0xffff0000u;      // high bf16 -> f32
    f32x2 r; r.x = a.f; r.y = b.f;
    return r;
}
static __device__ __forceinline__ unsigned short f2bf(float f) {
    union { float f; unsigned int i; } v; v.f = f;
    unsigned int u = v.i;
    unsigned int r = (u + 0x7fffu + ((u >> 16) & 1u)) >> 16;
    return (unsigned short)r;
}
static __device__ __forceinline__ unsigned int packbf(f32x2 v) {
    return (unsigned int)f2bf(v.x) | ((unsigned int)f2bf(v.y) << 16);
}

// ---- CDNA4 packed-FP32 helpers: one VOP3P = two FMAs.
static __device__ __forceinline__ void pk_fma(f32x2& acc, f32x2 v, f32x2 w) {
    asm("v_pk_fma_f32 %0, %1, %2, %0" : "+v"(acc) : "v"(v), "v"(w));
}
static __device__ __forceinline__ void pk_fma_lo(f32x2& acc, f32x2 v, f32x2 w) {
    asm("v_pk_fma_f32 %0, %1, %2, %0 op_sel:[0,0,0] op_sel_hi:[1,0,1]"
        : "+v"(acc) : "v"(v), "v"(w));
}
static __device__ __forceinline__ void pk_fma_hi(f32x2& acc, f32x2 v, f32x2 w) {
    asm("v_pk_fma_f32 %0, %1, %2, %0 op_sel:[0,1,0] op_sel_hi:[1,1,1]"
        : "+v"(acc) : "v"(v), "v"(w));
}
static __device__ __forceinline__ void pk_add(f32x2& acc, f32x2 v) {
    asm("v_pk_add_f32 %0, %1, %0" : "+v"(acc) : "v"(v));
}

// ================= bucketed CSR build (fixed-capacity slots) =================
// Round-13: packed FP32 halved FMA issue -> gat 50->46us only. Post-mortem:
// VALUBusy 63 / HBM 39% / issue-work ~10us vs 46us measured => LATENCY-bound
// gather (4 loads in flight/wave, ~5 waves/SIMD, ~500cy L2/L3 latency).
// Round-14: dwordx2 2-edges-per-load (lane halves own edges, 4 cols/lane),
// double-buffered chunk prefetch (8 edges/chunk), guard-zero at CONSUME time
// (cndmask on loaded reg at load time would force early vmcnt), EDGE_CAP
// 192->64 (LDS 15.4K->5.4K), drop gat __syncthreads (sAl/sSrc are wave-local
// -> waves decouple). Same restructure for k_build_sage's mean loop.
#define CPAD 16
#define PREP_CNT 107520
#define MAXBUCK 2048
#define BSLOT 1024
#define CH 8192

// ---------------- merged: scatter (blocks 0..scatB-1) | prep | xb ----------------
__global__ __launch_bounds__(256) void k_early(const float* __restrict__ x, int npairs,
                                               const int* __restrict__ ei, int E, int nbuck, int scatB,
                                               int* __restrict__ bcur,
                                               unsigned int* __restrict__ ebuf,
                                               const float* __restrict__ Wl, const float* __restrict__ Wr,
                                               const float* __restrict__ Wsrc, const float* __restrict__ Wlin,
                                               const float* __restrict__ Wdst,
                                               const float* __restrict__ atts, const float* __restrict__ attd,
                                               unsigned short* __restrict__ Bh,
                                               unsigned short* __restrict__ Bg,
                                               unsigned short* __restrict__ Bf,
                                               float* __restrict__ wsd,
                                               unsigned int* __restrict__ xb) {
    __shared__ unsigned int sval[CH];
    __shared__ unsigned short soff[CH];
    __shared__ int cnt[MAXBUCK];
    __shared__ int gbase[MAXBUCK];
    int gb = blockIdx.x, t = threadIdx.x;
    if (gb < scatB) {
        int c0 = gb * CH;
        int ecnt = E - c0; if (ecnt > CH) ecnt = CH;
        for (int i = t; i < MAXBUCK; i += 256) cnt[i] = 0;
        __syncthreads();
        for (int i = t; i < ecnt; i += 256) {
            int s = ei[c0 + i], d = ei[E + c0 + i];
            int b = d >> 5;
            soff[i] = (unsigned short)atomicAdd(&cnt[b], 1);
            sval[i] = (unsigned int)s | ((unsigned int)(d & 31) << 16) | ((unsigned int)b << 21);
        }
        __syncthreads();
        for (int b = t; b < nbuck; b += 256)
            if (cnt[b]) gbase[b] = (b << 10) + atomicAdd(&bcur[b * CPAD], cnt[b]);
        __syncthreads();
        for (int i = t; i < ecnt; i += 256) {
            unsigned int v = sval[i];
            int b = v >> 21;
            int pos = gbase[b] + soff[i];
            if (pos < ((b + 1) << 10)) ebuf[pos] = v & 0x1fffffu;  // cap (never hit)
        }
        return;
    }
    int i = (gb - scatB) * 256 + t;
    if (i < 32768) {                       // Bh: K=256, NCOL=128 (concat Wl;Wr)
        int idx = i;
        int j = idx & 7, n16 = (idx >> 3) & 15, quad = (idx >> 7) & 3, rest = idx >> 9;
        int nc = rest & 7, kb = rest >> 3;
        int kk = kb * 32 + quad * 8 + j;
        int n = nc * 16 + n16;
        float v = (kk < 128) ? Wl[kk * 128 + n] : Wr[(kk - 128) * 128 + n];
        Bh[idx] = f2bf(v);
    } else if (i < 32768 + 65536) {        // Bg: K=512, NCOL=128 (head-blocked Wsrc)
        int idx = i - 32768;
        int j = idx & 7, n16 = (idx >> 3) & 15, quad = (idx >> 7) & 3, rest = idx >> 9;
        int nc = rest & 7, kb = rest >> 3;
        int kk = kb * 32 + quad * 8 + j;
        int n = nc * 16 + n16;
        float v = Wsrc[(kk & 127) * 512 + (kk >> 7) * 128 + n];
        Bg[idx] = f2bf(v);
    } else if (i < 32768 + 65536 + 8192) { // Bf: K=128, NCOL=64 (Wlin)
        int idx = i - 98304;
        int j = idx & 7, n16 = (idx >> 3) & 15, quad = (idx >> 7) & 3, rest = idx >> 9;
        int nc = rest & 3, kb = rest >> 2;
        int kk = kb * 32 + quad * 8 + j;
        int n = nc * 16 + n16;
        Bf[idx] = f2bf(Wlin[kk * 64 + n]);
    } else if (i < PREP_CNT) {             // wsd -> transposed [o][132]
        int tt = i - 106496;
        int k = tt >> 3, o = tt & 7;
        int hh = o & 3;
        const float* W = (o < 4) ? Wsrc : Wdst;
        const float* att = (o < 4) ? atts : attd;
        float acc = 0.f;
        for (int c = 0; c < 128; c++) acc += W[k * 512 + hh * 128 + c] * att[hh * 128 + c];
        wsd[o * 132 + k] = acc;
    } else {                               // xb: x -> bf16 pairs
        int p = i - PREP_CNT;
        if (p < npairs) {
            float2 v = *(const float2*)(x + (size_t)p * 2);
            xb[p] = (unsigned int)f2bf(v.x) | ((unsigned int)f2bf(v.y) << 16);
        }
    }
}

// one block per bucket: in-LDS sort -> rowptr/rowend/csr, then fused SAGE mean
#define BCAP 1024
__global__ __launch_bounds__(256) void k_build_sage(const unsigned int* __restrict__ ebuf,
                                                    const int* __restrict__ bcur,
                                                    const unsigned int* __restrict__ xb,
                                                    int* __restrict__ csr,
                                                    int* __restrict__ rowptr,
                                                    int* __restrict__ rowend,
                                                    unsigned int* __restrict__ meanb, int N) {
    __shared__ int cnt[32];
    __shared__ int excl[33];
    __shared__ unsigned char off[BCAP];
    __shared__ unsigned int rawv[BCAP];
    __shared__ int sorted[BCAP];
    int b = blockIdx.x, t = threadIdx.x;
    int e0 = b << 10;
    int ecnt = bcur[b * CPAD];
    if (ecnt > BCAP) ecnt = BCAP;
    if (t < 32) cnt[t] = 0;
    __syncthreads();
    for (int i = t; i < ecnt; i += 256) {
        unsigned int p = ebuf[e0 + i];
        rawv[i] = p;
        off[i] = (unsigned char)atomicAdd(&cnt[(p >> 16) & 31], 1);
    }
    __syncthreads();
    if (t == 0) {
        int run = 0;
        #pragma unroll
        for (int j = 0; j < 32; j++) { excl[j] = run; run += cnt[j]; }
        excl[32] = run;
    }
    __syncthreads();
    for (int i = t; i < ecnt; i += 256) {
        unsigned int p = rawv[i];
        int d = (p >> 16) & 31;
        // store src<<6: the dword row offset for both xb and hb gathers
        sorted[excl[d] + off[i]] = (int)((p & 0xffffu) << 6);
    }
    __syncthreads();
    int nb0 = b << 5;
    if (t < 32 && nb0 + t < N) {
        rowptr[nb0 + t] = e0 + excl[t];
        rowend[nb0 + t] = e0 + excl[t + 1];
    }
    for (int i = t; i < ecnt; i += 256) csr[e0 + i] = sorted[i];
    // ---- fused SAGE mean: round-14 dwordx2 2-edge loads + dbuf prefetch ----
    int wv = t >> 6, lane = t & 63;
    int c2 = (lane & 31) << 1;   // dword-pair base within the 64-dword row
    int hf = lane >> 5;          // which edge of a pair this lane covers
    for (int k = 0; k < 8; k++) {
        int local = wv * 8 + k;
        int node = nb0 + local;
        if (node >= N) continue;
        int le0 = excl[local], le1 = excl[local + 1];
        int dg = le1 - le0;
        f32x2 aA = {0.f, 0.f}, aB = {0.f, 0.f};
        if (dg > 0) {
            u32x2 u0[4], u1[4];
            auto ld = [&](int base, u32x2* uu) {
                #pragma unroll
                for (int j = 0; j < 4; j++) {
                    int idx = base + 2 * j + hf;
                    int s64 = sorted[idx < le1 ? idx : le0];
                    uu[j] = *(const u32x2*)(xb + (unsigned)(s64 + c2));
                }
            };
            auto acc = [&](int base, u32x2* uu) {
                #pragma unroll
                for (int j = 0; j < 4; j++) {
                    int idx = base + 2 * j + hf;
                    u32x2 u = uu[j];
                    if (idx >= le1) { u[0] = 0u; u[1] = 0u; }   // zero AFTER load lands
                    pk_add(aA, bf2_to_p2(u[0]));
                    pk_add(aB, bf2_to_p2(u[1]));
                }
            };
            ld(le0, u0);
            int bb = le0 + 8;
            for (; bb < le1; bb += 8) {
                ld(bb, u1);                  // prefetch next chunk
                acc(bb - 8, u0);             // consume current
                #pragma unroll
                for (int j = 0; j < 4; j++) u0[j] = u1[j];
            }
            acc(bb - 8, u0);
        }
        aA.x += __shfl_xor(aA.x, 32);
        aA.y += __shfl_xor(aA.y, 32);
        aB.x += __shfl_xor(aB.x, 32);
        aB.y += __shfl_xor(aB.y, 32);
        if (lane < 32) {
            float inv = 1.0f / (float)(dg > 0 ? dg : 1);
            u32x2 o;
            f32x2 sa = aA; sa.x *= inv; sa.y *= inv;
            f32x2 sb = aB; sb.x *= inv; sb.y *= inv;
            o[0] = packbf(sa);
            o[1] = packbf(sb);
            __builtin_nontemporal_store(o, (u32x2*)(meanb + (size_t)node * 64 + c2));
        }
    }
}

// ---------------- MFMA GEMM (hb = relu([mean|x]@Bh + bs)) + fused a_s/a_d ----------------
__global__ __launch_bounds__(256) void k_mfma_h(const unsigned short* __restrict__ A0,
                                                const unsigned short* __restrict__ A1,
                                                const unsigned short* __restrict__ Bp,
                                                const float* __restrict__ bias,
                                                const float* __restrict__ wsd,
                                                unsigned short* __restrict__ outb,
                                                float* __restrict__ a_s,
                                                float* __restrict__ a_d, int M) {
    const int NC = 8;                       // NCOL = 128, K = 256
    __shared__ unsigned short sH[64][136];
    __shared__ float swsd[1056];            // [o][132] transposed+padded
    int tid = threadIdx.x;
    int wave = tid >> 6;
    int lane = tid & 63;
    int row0 = blockIdx.x * 64 + wave * 16;
    int n16 = lane & 15, quad = lane >> 4;
    int arow = row0 + n16;
    int arowc = arow < M ? arow : 0;
    for (int i = tid; i < 1056; i += 256) swsd[i] = wsd[i];
    f32x4 acc[NC];
    #pragma unroll
    for (int i = 0; i < NC; i++) acc[i] = (f32x4){0.f, 0.f, 0.f, 0.f};
    #pragma unroll
    for (int kb = 0; kb < 8; kb++) {
        const unsigned short* ap = (kb < 4)
            ? (A0 + (size_t)arowc * 128 + kb * 32 + quad * 8)
            : (A1 + (size_t)arowc * 128 + (kb - 4) * 32 + quad * 8);
        short8 af = *(const short8*)ap;
        #pragma unroll
        for (int nc = 0; nc < NC; nc++) {
            short8 bf = *(const short8*)(Bp + ((((size_t)(kb * NC + nc) * 4 + quad) * 16 + n16) << 3));
            acc[nc] = __builtin_amdgcn_mfma_f32_16x16x32_bf16(af, bf, acc[nc], 0, 0, 0);
        }
    }
    int orow = row0 + quad * 4;
    int lrow = wave * 16 + quad * 4;
    #pragma unroll
    for (int r = 0; r < 4; r++) {
        int m = orow + r;
        #pragma unroll
        for (int nc = 0; nc < NC; nc++) {
            int col = nc * 16 + n16;
            float v = fmaxf(acc[nc][r] + bias[col], 0.f);
            unsigned short bv = f2bf(v);
            sH[lrow + r][col] = bv;
            if (m < M) outb[(size_t)m * 128 + col] = bv;
        }
    }
    __syncthreads();
    // fused a_s/a_d: 64 rows x 8 outputs = 512 jobs, 2 per thread.
    #pragma unroll
    for (int j = tid; j < 512; j += 256) {
        int m = j >> 3, o = j & 7;
        const float* wr = swsd + o * 132;
        f32x2 pa = {0.f, 0.f}, pb = {0.f, 0.f};
        #pragma unroll 4
        for (int kb = 0; kb < 16; kb++) {
            const unsigned int* hp = (const unsigned int*)&sH[m][kb * 8];
            unsigned int h0 = hp[0], h1 = hp[1], h2 = hp[2], h3 = hp[3];
            f32x4 wa = *(const f32x4*)(wr + kb * 8);
            f32x4 wb = *(const f32x4*)(wr + kb * 8 + 4);
            pk_fma(pa, bf2_to_p2(h0), __builtin_shufflevector(wa, wa, 0, 1));
            pk_fma(pb, bf2_to_p2(h1), __builtin_shufflevector(wa, wa, 2, 3));
            pk_fma(pa, bf2_to_p2(h2), __builtin_shufflevector(wb, wb, 0, 1));
            pk_fma(pb, bf2_to_p2(h3), __builtin_shufflevector(wb, wb, 2, 3));
        }
        pk_add(pa, pb);
        float accd = pa.x + pa.y;
        int n = blockIdx.x * 64 + m;
        if (n < M) {
            if (o < 4) a_s[n * 4 + o] = accd;
            else       a_d[n * 4 + (o - 4)] = accd;
        }
    }
}

// ---------------- GAT: two-pass softmax aggregation ----------------
// round-14: dwordx2 2-edge loads, dbuf prefetch, EDGE_CAP 64, NO barrier
// (sSrc/sAl are wave-local -> waves run decoupled for latency hiding)
#define EDGE_CAP 64
__global__ __launch_bounds__(256) void k_gat_agg(const int* __restrict__ rowptr,
                                                 const int* __restrict__ rowend,
                                                 const int* __restrict__ csr,
                                                 const unsigned int* __restrict__ hb,
                                                 const float* __restrict__ a_s,
                                                 const float* __restrict__ a_d,
                                                 unsigned int* __restrict__ aggb, int N) {
    __shared__ int   sSrc[4][EDGE_CAP];
    __shared__ float sAl[4][EDGE_CAP * 4];
    int wv = threadIdx.x >> 6;
    int lane = threadIdx.x & 63;
    int n = blockIdx.x * 4 + wv;
    bool active = n < N;
    int e0 = 0, deg = 0;
    float4 ad = {0.f, 0.f, 0.f, 0.f};
    if (active) {
        e0 = rowptr[n];
        deg = rowend[n] - e0;
        ad = *(const float4*)(a_d + (size_t)n * 4);
    }
    // pass 1: per-edge weights (coalesced), partial denom in registers
    f32x4 psum = {0.f, 0.f, 0.f, 0.f};
    for (int base = 0; base < deg; base += 64) {
        int i = base + lane;
        if (i < deg) {
            int s64 = csr[e0 + i];                       // src<<6
            float4 as = *(const float4*)(a_s + (size_t)(s64 >> 4)); // src*4
            f32x4 w;
            w.x = __expf(leaky(as.x + ad.x));
            w.y = __expf(leaky(as.y + ad.y));
            w.z = __expf(leaky(as.z + ad.z));
            w.w = __expf(leaky(as.w + ad.w));
            psum += w;
            if (i < EDGE_CAP) {
                sSrc[wv][i] = s64;
                *(f32x4*)&sAl[wv][i * 4] = w;
            }
        }
    }
    #pragma unroll
    for (int o = 32; o; o >>= 1) {
        psum.x += __shfl_xor(psum.x, o);
        psum.y += __shfl_xor(psum.y, o);
        psum.z += __shfl_xor(psum.z, o);
        psum.w += __shfl_xor(psum.w, o);
    }
    f32x4 inv;
    inv.x = psum.x > 0.f ? 0.25f / psum.x : 0.f;
    inv.y = psum.y > 0.f ? 0.25f / psum.y : 0.f;
    inv.z = psum.z > 0.f ? 0.25f / psum.z : 0.f;
    inv.w = psum.w > 0.f ? 0.25f / psum.w : 0.f;
    int capdeg = deg < EDGE_CAP ? deg : EDGE_CAP;
    {
        int i = lane;
        if (i < capdeg) {
            f32x4 w = *(f32x4*)&sAl[wv][i * 4];
            w *= inv;
            *(f32x4*)&sAl[wv][i * 4] = w;
        }
    }
    // (no __syncthreads: sSrc/sAl strictly wave-local)
    // pass 2: weighted gather, 2 edges per dwordx2 load, dbuf prefetch
    int c2 = (lane & 31) << 1;   // dword-pair base within the 64-dword row
    int hf = lane >> 5;          // which edge of a pair this lane covers
    f32x2 a0l = {0.f,0.f}, a0h = {0.f,0.f}, a1l = {0.f,0.f}, a1h = {0.f,0.f};
    f32x2 a2l = {0.f,0.f}, a2h = {0.f,0.f}, a3l = {0.f,0.f}, a3h = {0.f,0.f};
    if (capdeg > 0) {
        u32x2 u0[4], u1[4];
        auto ld = [&](int base, u32x2* uu) {
            #pragma unroll
            for (int j = 0; j < 4; j++) {
                int idx = base + 2 * j + hf;
                int s64 = sSrc[wv][idx < capdeg ? idx : 0];
                uu[j] = *(const u32x2*)(hb + (unsigned)(s64 + c2));
            }
        };
        auto cons = [&](int base, u32x2* uu) {
            #pragma unroll
            for (int j = 0; j < 4; j++) {
                int idx = base + 2 * j + hf;
                u32x2 u = uu[j];
                if (idx >= capdeg) { u[0] = 0u; u[1] = 0u; }   // zero AFTER load lands
                const f32x4 w4 = *(const f32x4*)&sAl[wv][(idx < capdeg ? idx : 0) * 4];
                f32x2 wa = __builtin_shufflevector(w4, w4, 0, 1);
                f32x2 wb = __builtin_shufflevector(w4, w4, 2, 3);
                f32x2 p0 = bf2_to_p2(u[0]);
                f32x2 p1 = bf2_to_p2(u[1]);
                pk_fma_lo(a0l, p0, wa); pk_fma_lo(a0h, p1, wa);
                pk_fma_hi(a1l, p0, wa); pk_fma_hi(a1h, p1, wa);
                pk_fma_lo(a2l, p0, wb); pk_fma_lo(a2h, p1, wb);
                pk_fma_hi(a3l, p0, wb); pk_fma_hi(a3h, p1, wb);
            }
        };
        ld(0, u0);
        int bb = 8;
        for (; bb < capdeg; bb += 8) {
            ld(bb, u1);                  // prefetch next chunk
            cons(bb - 8, u0);            // consume current
            #pragma unroll
            for (int j = 0; j < 4; j++) u0[j] = u1[j];
        }
        cons(bb - 8, u0);
    }
    for (int i = EDGE_CAP; i < deg; i++) {   // overflow (statistically never)
        int s64 = csr[e0 + i];
        float4 as = *(const float4*)(a_s + (size_t)(s64 >> 4));
        f32x4 w;
        w.x = __expf(leaky(as.x + ad.x)) * inv.x;
        w.y = __expf(leaky(as.y + ad.y)) * inv.y;
        w.z = __expf(leaky(as.z + ad.z)) * inv.z;
        w.w = __expf(leaky(as.w + ad.w)) * inv.w;
        if (!hf) {                            // half 0 only (halves are summed later)
            u32x2 u = *(const u32x2*)(hb + (unsigned)(s64 + c2));
            f32x2 p0 = bf2_to_p2(u[0]);
            f32x2 p1 = bf2_to_p2(u[1]);
            f32x2 wa = __builtin_shufflevector(w, w, 0, 1);
            f32x2 wb = __builtin_shufflevector(w, w, 2, 3);
            pk_fma_lo(a0l, p0, wa); pk_fma_lo(a0h, p1, wa);
            pk_fma_hi(a1l, p0, wa); pk_fma_hi(a1h, p1, wa);
            pk_fma_lo(a2l, p0, wb); pk_fma_lo(a2h, p1, wb);
            pk_fma_hi(a3l, p0, wb); pk_fma_hi(a3h, p1, wb);
        }
    }
    if (!active) return;
    // cross-half reduce: lanes l and l+32 hold the two edge-subsets of same cols
    a0l.x += __shfl_xor(a0l.x, 32); a0l.y += __shfl_xor(a0l.y, 32);
    a0h.x += __shfl_xor(a0h.x, 32); a0h.y += __shfl_xor(a0h.y, 32);
    a1l.x += __shfl_xor(a1l.x, 32); a1l.y += __shfl_xor(a1l.y, 32);
    a1h.x += __shfl_xor(a1h.x, 32); a1h.y += __shfl_xor(a1h.y, 32);
    a2l.x += __shfl_xor(a2l.x, 32); a2l.y += __shfl_xor(a2l.y, 32);
    a2h.x += __shfl_xor(a2h.x, 32); a2h.y += __shfl_xor(a2h.y, 32);
    a3l.x += __shfl_xor(a3l.x, 32); a3l.y += __shfl_xor(a3l.y, 32);
    a3h.x += __shfl_xor(a3h.x, 32); a3h.y += __shfl_xor(a3h.y, 32);
    if (lane < 32) {
        unsigned int* rowu = aggb + (size_t)n * 256 + c2;
        u32x2 o;
        o[0] = packbf(a0l); o[1] = packbf(a0h);
        __builtin_nontemporal_store(o, (u32x2*)(rowu));
        o[0] = packbf(a1l); o[1] = packbf(a1h);
        __builtin_nontemporal_store(o, (u32x2*)(rowu + 64));
        o[0] = packbf(a2l); o[1] = packbf(a2h);
        __builtin_nontemporal_store(o, (u32x2*)(rowu + 128));
        o[0] = packbf(a3l); o[1] = packbf(a3h);
        __builtin_nontemporal_store(o, (u32x2*)(rowu + 192));
    }
}

// ---------------- fused tail: g = relu(aggb @ Bg + bg); out = g @ Bf + bl ----------------
__global__ __launch_bounds__(256) void k_mfma_tail(const unsigned short* __restrict__ aggb,
                                                   const unsigned short* __restrict__ Bg,
                                                   const float* __restrict__ bg,
                                                   const unsigned short* __restrict__ Bf,
                                                   const float* __restrict__ bl,
                                                   float* __restrict__ out, int M) {
    __shared__ unsigned short sG[64][136];   // +8-short pad -> only 2-way (free) LDS aliasing
    int wave = threadIdx.x >> 6;
    int lane = threadIdx.x & 63;
    int row0 = blockIdx.x * 64 + wave * 16;
    int n16 = lane & 15, quad = lane >> 4;
    // ---- stage 1: K=512, NCOL=128 ----
    {
        int arow = row0 + n16;
        int arowc = arow < M ? arow : 0;
        const unsigned short* ap = aggb + (size_t)arowc * 512 + quad * 8;
        f32x4 acc[8];
        #pragma unroll
        for (int i = 0; i < 8; i++) acc[i] = (f32x4){0.f, 0.f, 0.f, 0.f};
        #pragma unroll
        for (int kb = 0; kb < 16; kb++) {
            short8 af = *(const short8*)(ap + kb * 32);
            #pragma unroll
            for (int nc = 0; nc < 8; nc++) {
                short8 bf = *(const short8*)(Bg + ((((size_t)(kb * 8 + nc) * 4 + quad) * 16 + n16) << 3));
                acc[nc] = __builtin_amdgcn_mfma_f32_16x16x32_bf16(af, bf, acc[nc], 0, 0, 0);
            }
        }
        int lrow = wave * 16 + quad * 4;
        #pragma unroll
        for (int r = 0; r < 4; r++) {
            #pragma unroll
            for (int nc = 0; nc < 8; nc++) {
                int col = nc * 16 + n16;
                sG[lrow + r][col] = f2bf(fmaxf(acc[nc][r] + bg[col], 0.f));
            }
        }
    }
    __syncthreads();
    // ---- stage 2: K=128, NCOL=64 from LDS ----
    {
        f32x4 acc[4];
        #pragma unroll
        for (int i = 0; i < 4; i++) acc[i] = (f32x4){0.f, 0.f, 0.f, 0.f};
        #pragma unroll
        for (int kb = 0; kb < 4; kb++) {
            short8 af = *(const short8*)&sG[wave * 16 + n16][kb * 32 + quad * 8];
            #pragma unroll
            for (int nc = 0; nc < 4; nc++) {
                short8 bf = *(const short8*)(Bf + ((((size_t)(kb * 4 + nc) * 4 + quad) * 16 + n16) << 3));
                acc[nc] = __builtin_amdgcn_mfma_f32_16x16x32_bf16(af, bf, acc[nc], 0, 0, 0);
            }
        }
        int orow = row0 + quad * 4;
        #pragma unroll
        for (int r = 0; r < 4; r++) {
            int m = orow + r;
            if (m < M) {
                #pragma unroll
                for (int nc = 0; nc < 4; nc++) {
                    int col = nc * 16 + n16;
                    out[(size_t)m * 64 + col] = acc[nc][r] + bl[col];
                }
            }
        }
    }
}

extern "C" void kernel_launch(void* const* d_in, const int* in_sizes, int n_in,
                              void* d_out, int out_size, void* d_ws, size_t ws_size,
                              hipStream_t stream) {
    const float* x    = (const float*)d_in[0];
    const int*   ei   = (const int*)d_in[1];
    const float* Wl   = (const float*)d_in[2];
    const float* Wr   = (const float*)d_in[3];
    const float* bs   = (const float*)d_in[4];
    const float* Wsrc = (const float*)d_in[5];
    const float* Wdst = (const float*)d_in[6];
    const float* atts = (const float*)d_in[7];
    const float* attd = (const float*)d_in[8];
    const float* bg   = (const float*)d_in[9];
    const float* Wlin = (const float*)d_in[10];
    const float* bl   = (const float*)d_in[11];
    int N = in_sizes[0] / D;
    int E = in_sizes[1] / 2;
    int nbuck = (N + 31) >> 5;   // 1563 for N=50000
    int npairs = N * 64;

    char* w = (char*)d_ws;
    auto alloc = [&](size_t bytes) {
        char* p = w;
        w += (bytes + 255) & ~(size_t)255;
        return p;
    };
    unsigned int* xb     = (unsigned int*)alloc((size_t)N * 256);   // [N,128] bf16
    unsigned int* meanb  = (unsigned int*)alloc((size_t)N * 256);   // [N,128] bf16
    unsigned int* hb     = (unsigned int*)alloc((size_t)N * 256);   // [N,128] bf16
    unsigned int* aggb   = (unsigned int*)alloc((size_t)N * 1024);  // [N,512] bf16
    unsigned short* Bh   = (unsigned short*)alloc(65536 * 2);
    unsigned short* Bg   = (unsigned short*)alloc(65536 * 2);
    unsigned short* Bf   = (unsigned short*)alloc(8192 * 2);
    float* a_s           = (float*)alloc((size_t)N * 16);
    float* a_d           = (float*)alloc((size_t)N * 16);
    float* wsd           = (float*)alloc(1056 * 4);                 // [8][132] transposed
    int* rowptr          = (int*)alloc((size_t)N * 4);
    int* rowend          = (int*)alloc((size_t)N * 4);
    int* bcur            = (int*)alloc((size_t)MAXBUCK * CPAD * 4); // one 64B line per bucket
    unsigned int* ebuf   = (unsigned int*)alloc((size_t)MAXBUCK * BSLOT * 4); // bucket-padded
    int* csr             = (int*)alloc((size_t)MAXBUCK * BSLOT * 4);          // bucket-padded
    (void)ws_size; (void)n_in; (void)out_size;

    hipMemsetAsync(bcur, 0, (size_t)MAXBUCK * CPAD * 4, stream);

    int scatB = (E + CH - 1) / CH;
    int workBlocks = (PREP_CNT + npairs + 255) / 256;
    k_early<<<scatB + workBlocks, 256, 0, stream>>>(x, npairs, ei, E, nbuck, scatB,
                                                    bcur, ebuf,
                                                    Wl, Wr, Wsrc, Wlin, Wdst, atts, attd,
                                                    Bh, Bg, Bf, wsd, xb);
    k_build_sage<<<nbuck, 256, 0, stream>>>(ebuf, bcur, xb, csr, rowptr, rowend, meanb, N);

    k_mfma_h<<<(N + 63) / 64, 256, 0, stream>>>((const unsigned short*)meanb,
                                                (const unsigned short*)xb, Bh, bs, wsd,
                                                (unsigned short*)hb, a_s, a_d, N);
    k_gat_agg<<<(N + 3) / 4, 256, 0, stream>>>(rowptr, rowend, csr, hb, a_s, a_d, aggb, N);
    k_mfma_tail<<<(N + 63) / 64, 256, 0, stream>>>((const unsigned short*)aggb, Bg, bg,
                                                   Bf, bl, (float*)d_out, N);
}

// Round 4
// 240.296 us; speedup vs baseline: 1.0452x; 1.0452x over previous
//
#include <hip/hip_runtime.h>

#define D 128
#define HEADS 4

typedef __attribute__((ext_vector_type(8))) short short8;
typedef __attribute__((ext_vector_type(4))) float f32x4;
typedef __attribute__((ext_vector_type(2))) float f32x2;

static __device__ __forceinline__ float leaky(float v) { return v > 0.f ? v : 0.2f * v; }

static __device__ __forceinline__ f32x2 bf2_to_p2(unsigned int u) {
    union { unsigned int i; float f; } a, b;
    a.i = u << 16;              // low bf16 -> f32
    b.i = u & 0xffff0000u;      // high bf16 -> f32
    f32x2 r; r.x = a.f; r.y = b.f;
    return r;
}
static __device__ __forceinline__ unsigned short f2bf(float f) {
    union { float f; unsigned int i; } v; v.f = f;
    unsigned int u = v.i;
    unsigned int r = (u + 0x7fffu + ((u >> 16) & 1u)) >> 16;
    return (unsigned short)r;
}
// one instr, RNE -> bit-identical to f2bf pair (round-15)
static __device__ __forceinline__ unsigned int packbf(f32x2 v) {
    unsigned int r;
    asm("v_cvt_pk_bf16_f32 %0, %1, %2" : "=v"(r) : "v"(v.x), "v"(v.y));
    return r;
}

// ---- CDNA4 packed-FP32 helpers: one VOP3P = two FMAs.
static __device__ __forceinline__ void pk_fma(f32x2& acc, f32x2 v, f32x2 w) {
    asm("v_pk_fma_f32 %0, %1, %2, %0" : "+v"(acc) : "v"(v), "v"(w));
}
static __device__ __forceinline__ void pk_fma_lo(f32x2& acc, f32x2 v, f32x2 w) {
    asm("v_pk_fma_f32 %0, %1, %2, %0 op_sel:[0,0,0] op_sel_hi:[1,0,1]"
        : "+v"(acc) : "v"(v), "v"(w));
}
static __device__ __forceinline__ void pk_fma_hi(f32x2& acc, f32x2 v, f32x2 w) {
    asm("v_pk_fma_f32 %0, %1, %2, %0 op_sel:[0,1,0] op_sel_hi:[1,1,1]"
        : "+v"(acc) : "v"(v), "v"(w));
}
static __device__ __forceinline__ void pk_add(f32x2& acc, f32x2 v) {
    asm("v_pk_add_f32 %0, %1, %0" : "+v"(acc) : "v"(v));
}

// ================= bucketed CSR build (fixed-capacity slots) =================
// Round-14 post-mortem: dwordx2+guards ADDED ~50% issued instrs (VALU
// busy-time 29->44us) -> regressed. Instruction count is 1:1 with dur here;
// occupancy (51-64%) is dispatch dynamics, not resource caps.
// Round-15 (rerun; r15 bench was an infra failure, not a kernel failure):
// r13 structure restored + zero-cost levers only:
//   (1) no gat barrier (sSrc/sAl wave-local -> waves drift, hide latency)
//   (2) 128-thr/2-wave gat blocks (finer balance; 16WG/CU cap still -> 32 waves)
//   (3) v_cvt_pk_bf16_f32 packing (3 VALU -> 1 per pair, bit-identical RNE)
//   (4) sAl read as 2x f32x2 b64 (kills shufflevector reg-pair movs)
#define CPAD 16
#define PREP_CNT 107520
#define MAXBUCK 2048
#define BSLOT 1024
#define CH 8192

// ---------------- merged: scatter (blocks 0..scatB-1) | prep | xb ----------------
__global__ __launch_bounds__(256) void k_early(const float* __restrict__ x, int npairs,
                                               const int* __restrict__ ei, int E, int nbuck, int scatB,
                                               int* __restrict__ bcur,
                                               unsigned int* __restrict__ ebuf,
                                               const float* __restrict__ Wl, const float* __restrict__ Wr,
                                               const float* __restrict__ Wsrc, const float* __restrict__ Wlin,
                                               const float* __restrict__ Wdst,
                                               const float* __restrict__ atts, const float* __restrict__ attd,
                                               unsigned short* __restrict__ Bh,
                                               unsigned short* __restrict__ Bg,
                                               unsigned short* __restrict__ Bf,
                                               float* __restrict__ wsd,
                                               unsigned int* __restrict__ xb) {
    __shared__ unsigned int sval[CH];
    __shared__ unsigned short soff[CH];
    __shared__ int cnt[MAXBUCK];
    __shared__ int gbase[MAXBUCK];
    int gb = blockIdx.x, t = threadIdx.x;
    if (gb < scatB) {
        int c0 = gb * CH;
        int ecnt = E - c0; if (ecnt > CH) ecnt = CH;
        for (int i = t; i < MAXBUCK; i += 256) cnt[i] = 0;
        __syncthreads();
        for (int i = t; i < ecnt; i += 256) {
            int s = ei[c0 + i], d = ei[E + c0 + i];
            int b = d >> 5;
            soff[i] = (unsigned short)atomicAdd(&cnt[b], 1);
            sval[i] = (unsigned int)s | ((unsigned int)(d & 31) << 16) | ((unsigned int)b << 21);
        }
        __syncthreads();
        for (int b = t; b < nbuck; b += 256)
            if (cnt[b]) gbase[b] = (b << 10) + atomicAdd(&bcur[b * CPAD], cnt[b]);
        __syncthreads();
        for (int i = t; i < ecnt; i += 256) {
            unsigned int v = sval[i];
            int b = v >> 21;
            int pos = gbase[b] + soff[i];
            if (pos < ((b + 1) << 10)) ebuf[pos] = v & 0x1fffffu;  // cap (never hit)
        }
        return;
    }
    int i = (gb - scatB) * 256 + t;
    if (i < 32768) {                       // Bh: K=256, NCOL=128 (concat Wl;Wr)
        int idx = i;
        int j = idx & 7, n16 = (idx >> 3) & 15, quad = (idx >> 7) & 3, rest = idx >> 9;
        int nc = rest & 7, kb = rest >> 3;
        int kk = kb * 32 + quad * 8 + j;
        int n = nc * 16 + n16;
        float v = (kk < 128) ? Wl[kk * 128 + n] : Wr[(kk - 128) * 128 + n];
        Bh[idx] = f2bf(v);
    } else if (i < 32768 + 65536) {        // Bg: K=512, NCOL=128 (head-blocked Wsrc)
        int idx = i - 32768;
        int j = idx & 7, n16 = (idx >> 3) & 15, quad = (idx >> 7) & 3, rest = idx >> 9;
        int nc = rest & 7, kb = rest >> 3;
        int kk = kb * 32 + quad * 8 + j;
        int n = nc * 16 + n16;
        float v = Wsrc[(kk & 127) * 512 + (kk >> 7) * 128 + n];
        Bg[idx] = f2bf(v);
    } else if (i < 32768 + 65536 + 8192) { // Bf: K=128, NCOL=64 (Wlin)
        int idx = i - 98304;
        int j = idx & 7, n16 = (idx >> 3) & 15, quad = (idx >> 7) & 3, rest = idx >> 9;
        int nc = rest & 3, kb = rest >> 2;
        int kk = kb * 32 + quad * 8 + j;
        int n = nc * 16 + n16;
        Bf[idx] = f2bf(Wlin[kk * 64 + n]);
    } else if (i < PREP_CNT) {             // wsd -> transposed [o][132]
        int tt = i - 106496;
        int k = tt >> 3, o = tt & 7;
        int hh = o & 3;
        const float* W = (o < 4) ? Wsrc : Wdst;
        const float* att = (o < 4) ? atts : attd;
        float acc = 0.f;
        for (int c = 0; c < 128; c++) acc += W[k * 512 + hh * 128 + c] * att[hh * 128 + c];
        wsd[o * 132 + k] = acc;
    } else {                               // xb: x -> bf16 pairs
        int p = i - PREP_CNT;
        if (p < npairs) {
            float2 v = *(const float2*)(x + (size_t)p * 2);
            xb[p] = packbf((f32x2){v.x, v.y});
        }
    }
}

// one block per bucket: in-LDS sort -> rowptr/rowend/csr, then fused SAGE mean
#define BCAP 1024
__global__ __launch_bounds__(256) void k_build_sage(const unsigned int* __restrict__ ebuf,
                                                    const int* __restrict__ bcur,
                                                    const unsigned int* __restrict__ xb,
                                                    int* __restrict__ csr,
                                                    int* __restrict__ rowptr,
                                                    int* __restrict__ rowend,
                                                    unsigned int* __restrict__ meanb, int N) {
    __shared__ int cnt[32];
    __shared__ int excl[33];
    __shared__ unsigned char off[BCAP];
    __shared__ unsigned int rawv[BCAP];
    __shared__ int sorted[BCAP];
    int b = blockIdx.x, t = threadIdx.x;
    int e0 = b << 10;
    int ecnt = bcur[b * CPAD];
    if (ecnt > BCAP) ecnt = BCAP;
    if (t < 32) cnt[t] = 0;
    __syncthreads();
    for (int i = t; i < ecnt; i += 256) {
        unsigned int p = ebuf[e0 + i];
        rawv[i] = p;
        off[i] = (unsigned char)atomicAdd(&cnt[(p >> 16) & 31], 1);
    }
    __syncthreads();
    if (t == 0) {
        int run = 0;
        #pragma unroll
        for (int j = 0; j < 32; j++) { excl[j] = run; run += cnt[j]; }
        excl[32] = run;
    }
    __syncthreads();
    for (int i = t; i < ecnt; i += 256) {
        unsigned int p = rawv[i];
        int d = (p >> 16) & 31;
        // store src<<6: the dword row offset for both xb and hb gathers
        sorted[excl[d] + off[i]] = (int)((p & 0xffffu) << 6);
    }
    __syncthreads();
    int nb0 = b << 5;
    if (t < 32 && nb0 + t < N) {
        rowptr[nb0 + t] = e0 + excl[t];
        rowend[nb0 + t] = e0 + excl[t + 1];
    }
    for (int i = t; i < ecnt; i += 256) csr[e0 + i] = sorted[i];
    // ---- fused SAGE mean: 4 waves x 8 nodes, packed-f32 accumulate (r13 form) ----
    int wv = t >> 6, lane = t & 63;
    for (int k = 0; k < 8; k++) {
        int local = wv * 8 + k;
        int node = nb0 + local;
        if (node >= N) continue;
        int le0 = excl[local], le1 = excl[local + 1];
        f32x2 aA = {0.f, 0.f}, aB = {0.f, 0.f};
        int e = le0;
        for (; e + 3 < le1; e += 4) {
            int s0 = sorted[e], s1 = sorted[e + 1], s2 = sorted[e + 2], s3 = sorted[e + 3];
            unsigned int u0 = xb[(unsigned)(s0 + lane)];
            unsigned int u1 = xb[(unsigned)(s1 + lane)];
            unsigned int u2 = xb[(unsigned)(s2 + lane)];
            unsigned int u3 = xb[(unsigned)(s3 + lane)];
            pk_add(aA, bf2_to_p2(u0));
            pk_add(aB, bf2_to_p2(u1));
            pk_add(aA, bf2_to_p2(u2));
            pk_add(aB, bf2_to_p2(u3));
        }
        for (; e < le1; e++)
            pk_add(aA, bf2_to_p2(xb[(unsigned)(sorted[e] + lane)]));
        pk_add(aA, aB);
        int dg = le1 - le0;
        float inv = 1.0f / (float)(dg > 0 ? dg : 1);
        f32x2 sm = aA; sm.x *= inv; sm.y *= inv;
        unsigned int o = packbf(sm);
        __builtin_nontemporal_store(o, meanb + (size_t)node * 64 + lane);
    }
}

// ---------------- MFMA GEMM (hb = relu([mean|x]@Bh + bs)) + fused a_s/a_d ----------------
__global__ __launch_bounds__(256) void k_mfma_h(const unsigned short* __restrict__ A0,
                                                const unsigned short* __restrict__ A1,
                                                const unsigned short* __restrict__ Bp,
                                                const float* __restrict__ bias,
                                                const float* __restrict__ wsd,
                                                unsigned short* __restrict__ outb,
                                                float* __restrict__ a_s,
                                                float* __restrict__ a_d, int M) {
    const int NC = 8;                       // NCOL = 128, K = 256
    __shared__ unsigned short sH[64][136];
    __shared__ float swsd[1056];            // [o][132] transposed+padded
    int tid = threadIdx.x;
    int wave = tid >> 6;
    int lane = tid & 63;
    int row0 = blockIdx.x * 64 + wave * 16;
    int n16 = lane & 15, quad = lane >> 4;
    int arow = row0 + n16;
    int arowc = arow < M ? arow : 0;
    for (int i = tid; i < 1056; i += 256) swsd[i] = wsd[i];
    f32x4 acc[NC];
    #pragma unroll
    for (int i = 0; i < NC; i++) acc[i] = (f32x4){0.f, 0.f, 0.f, 0.f};
    #pragma unroll
    for (int kb = 0; kb < 8; kb++) {
        const unsigned short* ap = (kb < 4)
            ? (A0 + (size_t)arowc * 128 + kb * 32 + quad * 8)
            : (A1 + (size_t)arowc * 128 + (kb - 4) * 32 + quad * 8);
        short8 af = *(const short8*)ap;
        #pragma unroll
        for (int nc = 0; nc < NC; nc++) {
            short8 bf = *(const short8*)(Bp + ((((size_t)(kb * NC + nc) * 4 + quad) * 16 + n16) << 3));
            acc[nc] = __builtin_amdgcn_mfma_f32_16x16x32_bf16(af, bf, acc[nc], 0, 0, 0);
        }
    }
    int orow = row0 + quad * 4;
    int lrow = wave * 16 + quad * 4;
    #pragma unroll
    for (int r = 0; r < 4; r++) {
        int m = orow + r;
        #pragma unroll
        for (int nc = 0; nc < NC; nc++) {
            int col = nc * 16 + n16;
            float v = fmaxf(acc[nc][r] + bias[col], 0.f);
            unsigned short bv = f2bf(v);
            sH[lrow + r][col] = bv;
            if (m < M) outb[(size_t)m * 128 + col] = bv;
        }
    }
    __syncthreads();
    // fused a_s/a_d: 64 rows x 8 outputs = 512 jobs, 2 per thread.
    #pragma unroll
    for (int j = tid; j < 512; j += 256) {
        int m = j >> 3, o = j & 7;
        const float* wr = swsd + o * 132;
        f32x2 pa = {0.f, 0.f}, pb = {0.f, 0.f};
        #pragma unroll 4
        for (int kb = 0; kb < 16; kb++) {
            const unsigned int* hp = (const unsigned int*)&sH[m][kb * 8];
            unsigned int h0 = hp[0], h1 = hp[1], h2 = hp[2], h3 = hp[3];
            f32x2 wa0 = *(const f32x2*)(wr + kb * 8);
            f32x2 wa1 = *(const f32x2*)(wr + kb * 8 + 2);
            f32x2 wb0 = *(const f32x2*)(wr + kb * 8 + 4);
            f32x2 wb1 = *(const f32x2*)(wr + kb * 8 + 6);
            pk_fma(pa, bf2_to_p2(h0), wa0);
            pk_fma(pb, bf2_to_p2(h1), wa1);
            pk_fma(pa, bf2_to_p2(h2), wb0);
            pk_fma(pb, bf2_to_p2(h3), wb1);
        }
        pk_add(pa, pb);
        float accd = pa.x + pa.y;
        int n = blockIdx.x * 64 + m;
        if (n < M) {
            if (o < 4) a_s[n * 4 + o] = accd;
            else       a_d[n * 4 + (o - 4)] = accd;
        }
    }
}

// ---------------- GAT: two-pass softmax aggregation ----------------
// round-15: r13 inner structure; 2 waves/block (finer balance), NO barrier
// (sSrc/sAl wave-local), cvt_pk outputs, b64 weight loads.
#define EDGE_CAP 192
__global__ __launch_bounds__(128) void k_gat_agg(const int* __restrict__ rowptr,
                                                 const int* __restrict__ rowend,
                                                 const int* __restrict__ csr,
                                                 const unsigned int* __restrict__ hb,
                                                 const float* __restrict__ a_s,
                                                 const float* __restrict__ a_d,
                                                 unsigned int* __restrict__ aggb, int N) {
    __shared__ int   sSrc[2][EDGE_CAP];
    __shared__ float sAl[2][EDGE_CAP * 4];
    int wv = threadIdx.x >> 6;
    int lane = threadIdx.x & 63;
    int n = blockIdx.x * 2 + wv;
    bool active = n < N;
    int e0 = 0, deg = 0;
    float4 ad = {0.f, 0.f, 0.f, 0.f};
    if (active) {
        e0 = rowptr[n];
        deg = rowend[n] - e0;
        ad = *(const float4*)(a_d + (size_t)n * 4);
    }
    // pass 1: per-edge weights (coalesced), partial denom in registers
    f32x4 psum = {0.f, 0.f, 0.f, 0.f};
    for (int base = 0; base < deg; base += 64) {
        int i = base + lane;
        if (i < deg) {
            int s64 = csr[e0 + i];                       // src<<6
            float4 as = *(const float4*)(a_s + (size_t)(s64 >> 4)); // src*4
            f32x4 w;
            w.x = __expf(leaky(as.x + ad.x));
            w.y = __expf(leaky(as.y + ad.y));
            w.z = __expf(leaky(as.z + ad.z));
            w.w = __expf(leaky(as.w + ad.w));
            psum += w;
            if (i < EDGE_CAP) {
                sSrc[wv][i] = s64;
                *(f32x4*)&sAl[wv][i * 4] = w;
            }
        }
    }
    #pragma unroll
    for (int o = 32; o; o >>= 1) {
        psum.x += __shfl_xor(psum.x, o);
        psum.y += __shfl_xor(psum.y, o);
        psum.z += __shfl_xor(psum.z, o);
        psum.w += __shfl_xor(psum.w, o);
    }
    f32x4 inv;
    inv.x = psum.x > 0.f ? 0.25f / psum.x : 0.f;
    inv.y = psum.y > 0.f ? 0.25f / psum.y : 0.f;
    inv.z = psum.z > 0.f ? 0.25f / psum.z : 0.f;
    inv.w = psum.w > 0.f ? 0.25f / psum.w : 0.f;
    int capdeg = deg < EDGE_CAP ? deg : EDGE_CAP;
    for (int base = 0; base < capdeg; base += 64) {
        int i = base + lane;
        if (i < capdeg) {
            f32x4 w = *(f32x4*)&sAl[wv][i * 4];
            w *= inv;
            *(f32x4*)&sAl[wv][i * 4] = w;
        }
    }
    // NO __syncthreads: sSrc/sAl strictly wave-local; waves drift apart
    // pass 2: weighted gather with LDS-broadcast weights (b64 pair loads)
    f32x2 ac0 = {0.f, 0.f}, ac1 = {0.f, 0.f}, ac2 = {0.f, 0.f}, ac3 = {0.f, 0.f};
    int e = 0;
    for (; e + 3 < capdeg; e += 4) {
        int o0 = sSrc[wv][e], o1 = sSrc[wv][e + 1], o2 = sSrc[wv][e + 2], o3 = sSrc[wv][e + 3];
        unsigned int u0 = hb[(unsigned)(o0 + lane)];
        unsigned int u1 = hb[(unsigned)(o1 + lane)];
        unsigned int u2 = hb[(unsigned)(o2 + lane)];
        unsigned int u3 = hb[(unsigned)(o3 + lane)];
        f32x2 w0a = *(const f32x2*)&sAl[wv][e * 4];
        f32x2 w0b = *(const f32x2*)&sAl[wv][e * 4 + 2];
        f32x2 w1a = *(const f32x2*)&sAl[wv][e * 4 + 4];
        f32x2 w1b = *(const f32x2*)&sAl[wv][e * 4 + 6];
        f32x2 w2a = *(const f32x2*)&sAl[wv][e * 4 + 8];
        f32x2 w2b = *(const f32x2*)&sAl[wv][e * 4 + 10];
        f32x2 w3a = *(const f32x2*)&sAl[wv][e * 4 + 12];
        f32x2 w3b = *(const f32x2*)&sAl[wv][e * 4 + 14];
        f32x2 v0 = bf2_to_p2(u0), v1 = bf2_to_p2(u1), v2 = bf2_to_p2(u2), v3 = bf2_to_p2(u3);
        pk_fma_lo(ac0, v0, w0a); pk_fma_hi(ac1, v0, w0a); pk_fma_lo(ac2, v0, w0b); pk_fma_hi(ac3, v0, w0b);
        pk_fma_lo(ac0, v1, w1a); pk_fma_hi(ac1, v1, w1a); pk_fma_lo(ac2, v1, w1b); pk_fma_hi(ac3, v1, w1b);
        pk_fma_lo(ac0, v2, w2a); pk_fma_hi(ac1, v2, w2a); pk_fma_lo(ac2, v2, w2b); pk_fma_hi(ac3, v2, w2b);
        pk_fma_lo(ac0, v3, w3a); pk_fma_hi(ac1, v3, w3a); pk_fma_lo(ac2, v3, w3b); pk_fma_hi(ac3, v3, w3b);
    }
    for (; e < capdeg; e++) {
        int o0 = sSrc[wv][e];
        unsigned int u0 = hb[(unsigned)(o0 + lane)];
        f32x2 wa = *(const f32x2*)&sAl[wv][e * 4];
        f32x2 wb = *(const f32x2*)&sAl[wv][e * 4 + 2];
        f32x2 v0 = bf2_to_p2(u0);
        pk_fma_lo(ac0, v0, wa); pk_fma_hi(ac1, v0, wa);
        pk_fma_lo(ac2, v0, wb); pk_fma_hi(ac3, v0, wb);
    }
    for (int i = EDGE_CAP; i < deg; i++) {   // overflow (statistically never)
        int s64 = csr[e0 + i];
        float4 as = *(const float4*)(a_s + (size_t)(s64 >> 4));
        f32x4 w;
        w.x = __expf(leaky(as.x + ad.x)) * inv.x;
        w.y = __expf(leaky(as.y + ad.y)) * inv.y;
        w.z = __expf(leaky(as.z + ad.z)) * inv.z;
        w.w = __expf(leaky(as.w + ad.w)) * inv.w;
        f32x2 v0 = bf2_to_p2(hb[(unsigned)(s64 + lane)]);
        f32x2 wa = {w.x, w.y}, wb = {w.z, w.w};
        pk_fma_lo(ac0, v0, wa); pk_fma_hi(ac1, v0, wa);
        pk_fma_lo(ac2, v0, wb); pk_fma_hi(ac3, v0, wb);
    }
    if (!active) return;
    unsigned int* rowu = aggb + (size_t)n * 256 + lane;
    __builtin_nontemporal_store(packbf(ac0), rowu + 0);
    __builtin_nontemporal_store(packbf(ac1), rowu + 64);
    __builtin_nontemporal_store(packbf(ac2), rowu + 128);
    __builtin_nontemporal_store(packbf(ac3), rowu + 192);
}

// ---------------- fused tail: g = relu(aggb @ Bg + bg); out = g @ Bf + bl ----------------
__global__ __launch_bounds__(256) void k_mfma_tail(const unsigned short* __restrict__ aggb,
                                                   const unsigned short* __restrict__ Bg,
                                                   const float* __restrict__ bg,
                                                   const unsigned short* __restrict__ Bf,
                                                   const float* __restrict__ bl,
                                                   float* __restrict__ out, int M) {
    __shared__ unsigned short sG[64][136];   // +8-short pad -> only 2-way (free) LDS aliasing
    int wave = threadIdx.x >> 6;
    int lane = threadIdx.x & 63;
    int row0 = blockIdx.x * 64 + wave * 16;
    int n16 = lane & 15, quad = lane >> 4;
    // ---- stage 1: K=512, NCOL=128 ----
    {
        int arow = row0 + n16;
        int arowc = arow < M ? arow : 0;
        const unsigned short* ap = aggb + (size_t)arowc * 512 + quad * 8;
        f32x4 acc[8];
        #pragma unroll
        for (int i = 0; i < 8; i++) acc[i] = (f32x4){0.f, 0.f, 0.f, 0.f};
        #pragma unroll
        for (int kb = 0; kb < 16; kb++) {
            short8 af = *(const short8*)(ap + kb * 32);
            #pragma unroll
            for (int nc = 0; nc < 8; nc++) {
                short8 bf = *(const short8*)(Bg + ((((size_t)(kb * 8 + nc) * 4 + quad) * 16 + n16) << 3));
                acc[nc] = __builtin_amdgcn_mfma_f32_16x16x32_bf16(af, bf, acc[nc], 0, 0, 0);
            }
        }
        int lrow = wave * 16 + quad * 4;
        #pragma unroll
        for (int r = 0; r < 4; r++) {
            #pragma unroll
            for (int nc = 0; nc < 8; nc++) {
                int col = nc * 16 + n16;
                sG[lrow + r][col] = f2bf(fmaxf(acc[nc][r] + bg[col], 0.f));
            }
        }
    }
    __syncthreads();
    // ---- stage 2: K=128, NCOL=64 from LDS ----
    {
        f32x4 acc[4];
        #pragma unroll
        for (int i = 0; i < 4; i++) acc[i] = (f32x4){0.f, 0.f, 0.f, 0.f};
        #pragma unroll
        for (int kb = 0; kb < 4; kb++) {
            short8 af = *(const short8*)&sG[wave * 16 + n16][kb * 32 + quad * 8];
            #pragma unroll
            for (int nc = 0; nc < 4; nc++) {
                short8 bf = *(const short8*)(Bf + ((((size_t)(kb * 4 + nc) * 4 + quad) * 16 + n16) << 3));
                acc[nc] = __builtin_amdgcn_mfma_f32_16x16x32_bf16(af, bf, acc[nc], 0, 0, 0);
            }
        }
        int orow = row0 + quad * 4;
        #pragma unroll
        for (int r = 0; r < 4; r++) {
            int m = orow + r;
            if (m < M) {
                #pragma unroll
                for (int nc = 0; nc < 4; nc++) {
                    int col = nc * 16 + n16;
                    out[(size_t)m * 64 + col] = acc[nc][r] + bl[col];
                }
            }
        }
    }
}

extern "C" void kernel_launch(void* const* d_in, const int* in_sizes, int n_in,
                              void* d_out, int out_size, void* d_ws, size_t ws_size,
                              hipStream_t stream) {
    const float* x    = (const float*)d_in[0];
    const int*   ei   = (const int*)d_in[1];
    const float* Wl   = (const float*)d_in[2];
    const float* Wr   = (const float*)d_in[3];
    const float* bs   = (const float*)d_in[4];
    const float* Wsrc = (const float*)d_in[5];
    const float* Wdst = (const float*)d_in[6];
    const float* atts = (const float*)d_in[7];
    const float* attd = (const float*)d_in[8];
    const float* bg   = (const float*)d_in[9];
    const float* Wlin = (const float*)d_in[10];
    const float* bl   = (const float*)d_in[11];
    int N = in_sizes[0] / D;
    int E = in_sizes[1] / 2;
    int nbuck = (N + 31) >> 5;   // 1563 for N=50000
    int npairs = N * 64;

    char* w = (char*)d_ws;
    auto alloc = [&](size_t bytes) {
        char* p = w;
        w += (bytes + 255) & ~(size_t)255;
        return p;
    };
    unsigned int* xb     = (unsigned int*)alloc((size_t)N * 256);   // [N,128] bf16
    unsigned int* meanb  = (unsigned int*)alloc((size_t)N * 256);   // [N,128] bf16
    unsigned int* hb     = (unsigned int*)alloc((size_t)N * 256);   // [N,128] bf16
    unsigned int* aggb   = (unsigned int*)alloc((size_t)N * 1024);  // [N,512] bf16
    unsigned short* Bh   = (unsigned short*)alloc(65536 * 2);
    unsigned short* Bg   = (unsigned short*)alloc(65536 * 2);
    unsigned short* Bf   = (unsigned short*)alloc(8192 * 2);
    float* a_s           = (float*)alloc((size_t)N * 16);
    float* a_d           = (float*)alloc((size_t)N * 16);
    float* wsd           = (float*)alloc(1056 * 4);                 // [8][132] transposed
    int* rowptr          = (int*)alloc((size_t)N * 4);
    int* rowend          = (int*)alloc((size_t)N * 4);
    int* bcur            = (int*)alloc((size_t)MAXBUCK * CPAD * 4); // one 64B line per bucket
    unsigned int* ebuf   = (unsigned int*)alloc((size_t)MAXBUCK * BSLOT * 4); // bucket-padded
    int* csr             = (int*)alloc((size_t)MAXBUCK * BSLOT * 4);          // bucket-padded
    (void)ws_size; (void)n_in; (void)out_size;

    hipMemsetAsync(bcur, 0, (size_t)MAXBUCK * CPAD * 4, stream);

    int scatB = (E + CH - 1) / CH;
    int workBlocks = (PREP_CNT + npairs + 255) / 256;
    k_early<<<scatB + workBlocks, 256, 0, stream>>>(x, npairs, ei, E, nbuck, scatB,
                                                    bcur, ebuf,
                                                    Wl, Wr, Wsrc, Wlin, Wdst, atts, attd,
                                                    Bh, Bg, Bf, wsd, xb);
    k_build_sage<<<nbuck, 256, 0, stream>>>(ebuf, bcur, xb, csr, rowptr, rowend, meanb, N);

    k_mfma_h<<<(N + 63) / 64, 256, 0, stream>>>((const unsigned short*)meanb,
                                                (const unsigned short*)xb, Bh, bs, wsd,
                                                (unsigned short*)hb, a_s, a_d, N);
    k_gat_agg<<<(N + 1) / 2, 128, 0, stream>>>(rowptr, rowend, csr, hb, a_s, a_d, aggb, N);
    k_mfma_tail<<<(N + 63) / 64, 256, 0, stream>>>((const unsigned short*)aggb, Bg, bg,
                                                   Bf, bl, (float*)d_out, N);
}

// Round 5
// 235.499 us; speedup vs baseline: 1.0665x; 1.0204x over previous
//
#include <hip/hip_runtime.h>

#define D 128
#define HEADS 4

typedef __attribute__((ext_vector_type(8))) short short8;
typedef __attribute__((ext_vector_type(4))) float f32x4;
typedef __attribute__((ext_vector_type(2))) float f32x2;

static __device__ __forceinline__ float leaky(float v) { return v > 0.f ? v : 0.2f * v; }

static __device__ __forceinline__ f32x2 bf2_to_p2(unsigned int u) {
    union { unsigned int i; float f; } a, b;
    a.i = u << 16;              // low bf16 -> f32
    b.i = u & 0xffff0000u;      // high bf16 -> f32
    f32x2 r; r.x = a.f; r.y = b.f;
    return r;
}
static __device__ __forceinline__ unsigned short f2bf(float f) {
    union { float f; unsigned int i; } v; v.f = f;
    unsigned int u = v.i;
    unsigned int r = (u + 0x7fffu + ((u >> 16) & 1u)) >> 16;
    return (unsigned short)r;
}
// one instr, RNE -> bit-identical to f2bf pair
static __device__ __forceinline__ unsigned int packbf(f32x2 v) {
    unsigned int r;
    asm("v_cvt_pk_bf16_f32 %0, %1, %2" : "=v"(r) : "v"(v.x), "v"(v.y));
    return r;
}

// ---- CDNA4 packed-FP32 helpers: one VOP3P = two FMAs.
static __device__ __forceinline__ void pk_fma(f32x2& acc, f32x2 v, f32x2 w) {
    asm("v_pk_fma_f32 %0, %1, %2, %0" : "+v"(acc) : "v"(v), "v"(w));
}
static __device__ __forceinline__ void pk_fma_lo(f32x2& acc, f32x2 v, f32x2 w) {
    asm("v_pk_fma_f32 %0, %1, %2, %0 op_sel:[0,0,0] op_sel_hi:[1,0,1]"
        : "+v"(acc) : "v"(v), "v"(w));
}
static __device__ __forceinline__ void pk_fma_hi(f32x2& acc, f32x2 v, f32x2 w) {
    asm("v_pk_fma_f32 %0, %1, %2, %0 op_sel:[0,1,0] op_sel_hi:[1,1,1]"
        : "+v"(acc) : "v"(v), "v"(w));
}
static __device__ __forceinline__ void pk_add(f32x2& acc, f32x2 v) {
    asm("v_pk_add_f32 %0, %1, %0" : "+v"(acc) : "v"(v));
}

// ================= bucketed CSR build (fixed-capacity slots) =================
// Round-16: r15 landed gat 46.1->43.8us (VGPR 28, no barrier, 2-wave blocks).
// Residual diagnosed as gather MLP: 4 loads in flight/wave vs ~500cy latency.
// This round: pass-1 PADS the edge list to a multiple of 8 with zero-weight
// row-0 entries (kills pass-2 tail+guards entirely), pass-2 unrolls to 8
// loads in flight (VGPR ~44 < 64 -> no occupancy cliff), sources via 2x
// ds_read_b128, weights via 1x b128/edge. Same 8-deep tier in sage mean.
// (r14's regression was guard/copy instr bloat, NOT prefetch depth; r12's
// was the 256-thr/15KB config. Instruction count here goes DOWN.)
#define CPAD 16
#define PREP_CNT 107520
#define MAXBUCK 2048
#define BSLOT 1024
#define CH 8192

// ---------------- merged: scatter (blocks 0..scatB-1) | prep | xb ----------------
__global__ __launch_bounds__(256) void k_early(const float* __restrict__ x, int npairs,
                                               const int* __restrict__ ei, int E, int nbuck, int scatB,
                                               int* __restrict__ bcur,
                                               unsigned int* __restrict__ ebuf,
                                               const float* __restrict__ Wl, const float* __restrict__ Wr,
                                               const float* __restrict__ Wsrc, const float* __restrict__ Wlin,
                                               const float* __restrict__ Wdst,
                                               const float* __restrict__ atts, const float* __restrict__ attd,
                                               unsigned short* __restrict__ Bh,
                                               unsigned short* __restrict__ Bg,
                                               unsigned short* __restrict__ Bf,
                                               float* __restrict__ wsd,
                                               unsigned int* __restrict__ xb) {
    __shared__ unsigned int sval[CH];
    __shared__ unsigned short soff[CH];
    __shared__ int cnt[MAXBUCK];
    __shared__ int gbase[MAXBUCK];
    int gb = blockIdx.x, t = threadIdx.x;
    if (gb < scatB) {
        int c0 = gb * CH;
        int ecnt = E - c0; if (ecnt > CH) ecnt = CH;
        for (int i = t; i < MAXBUCK; i += 256) cnt[i] = 0;
        __syncthreads();
        for (int i = t; i < ecnt; i += 256) {
            int s = ei[c0 + i], d = ei[E + c0 + i];
            int b = d >> 5;
            soff[i] = (unsigned short)atomicAdd(&cnt[b], 1);
            sval[i] = (unsigned int)s | ((unsigned int)(d & 31) << 16) | ((unsigned int)b << 21);
        }
        __syncthreads();
        for (int b = t; b < nbuck; b += 256)
            if (cnt[b]) gbase[b] = (b << 10) + atomicAdd(&bcur[b * CPAD], cnt[b]);
        __syncthreads();
        for (int i = t; i < ecnt; i += 256) {
            unsigned int v = sval[i];
            int b = v >> 21;
            int pos = gbase[b] + soff[i];
            if (pos < ((b + 1) << 10)) ebuf[pos] = v & 0x1fffffu;  // cap (never hit)
        }
        return;
    }
    int i = (gb - scatB) * 256 + t;
    if (i < 32768) {                       // Bh: K=256, NCOL=128 (concat Wl;Wr)
        int idx = i;
        int j = idx & 7, n16 = (idx >> 3) & 15, quad = (idx >> 7) & 3, rest = idx >> 9;
        int nc = rest & 7, kb = rest >> 3;
        int kk = kb * 32 + quad * 8 + j;
        int n = nc * 16 + n16;
        float v = (kk < 128) ? Wl[kk * 128 + n] : Wr[(kk - 128) * 128 + n];
        Bh[idx] = f2bf(v);
    } else if (i < 32768 + 65536) {        // Bg: K=512, NCOL=128 (head-blocked Wsrc)
        int idx = i - 32768;
        int j = idx & 7, n16 = (idx >> 3) & 15, quad = (idx >> 7) & 3, rest = idx >> 9;
        int nc = rest & 7, kb = rest >> 3;
        int kk = kb * 32 + quad * 8 + j;
        int n = nc * 16 + n16;
        float v = Wsrc[(kk & 127) * 512 + (kk >> 7) * 128 + n];
        Bg[idx] = f2bf(v);
    } else if (i < 32768 + 65536 + 8192) { // Bf: K=128, NCOL=64 (Wlin)
        int idx = i - 98304;
        int j = idx & 7, n16 = (idx >> 3) & 15, quad = (idx >> 7) & 3, rest = idx >> 9;
        int nc = rest & 3, kb = rest >> 2;
        int kk = kb * 32 + quad * 8 + j;
        int n = nc * 16 + n16;
        Bf[idx] = f2bf(Wlin[kk * 64 + n]);
    } else if (i < PREP_CNT) {             // wsd -> transposed [o][132]
        int tt = i - 106496;
        int k = tt >> 3, o = tt & 7;
        int hh = o & 3;
        const float* W = (o < 4) ? Wsrc : Wdst;
        const float* att = (o < 4) ? atts : attd;
        float acc = 0.f;
        for (int c = 0; c < 128; c++) acc += W[k * 512 + hh * 128 + c] * att[hh * 128 + c];
        wsd[o * 132 + k] = acc;
    } else {                               // xb: x -> bf16 pairs
        int p = i - PREP_CNT;
        if (p < npairs) {
            float2 v = *(const float2*)(x + (size_t)p * 2);
            xb[p] = packbf((f32x2){v.x, v.y});
        }
    }
}

// one block per bucket: in-LDS sort -> rowptr/rowend/csr, then fused SAGE mean
#define BCAP 1024
__global__ __launch_bounds__(256) void k_build_sage(const unsigned int* __restrict__ ebuf,
                                                    const int* __restrict__ bcur,
                                                    const unsigned int* __restrict__ xb,
                                                    int* __restrict__ csr,
                                                    int* __restrict__ rowptr,
                                                    int* __restrict__ rowend,
                                                    unsigned int* __restrict__ meanb, int N) {
    __shared__ int cnt[32];
    __shared__ int excl[33];
    __shared__ unsigned char off[BCAP];
    __shared__ unsigned int rawv[BCAP];
    __shared__ int sorted[BCAP];
    int b = blockIdx.x, t = threadIdx.x;
    int e0 = b << 10;
    int ecnt = bcur[b * CPAD];
    if (ecnt > BCAP) ecnt = BCAP;
    if (t < 32) cnt[t] = 0;
    __syncthreads();
    for (int i = t; i < ecnt; i += 256) {
        unsigned int p = ebuf[e0 + i];
        rawv[i] = p;
        off[i] = (unsigned char)atomicAdd(&cnt[(p >> 16) & 31], 1);
    }
    __syncthreads();
    if (t == 0) {
        int run = 0;
        #pragma unroll
        for (int j = 0; j < 32; j++) { excl[j] = run; run += cnt[j]; }
        excl[32] = run;
    }
    __syncthreads();
    for (int i = t; i < ecnt; i += 256) {
        unsigned int p = rawv[i];
        int d = (p >> 16) & 31;
        // store src<<6: the dword row offset for both xb and hb gathers
        sorted[excl[d] + off[i]] = (int)((p & 0xffffu) << 6);
    }
    __syncthreads();
    int nb0 = b << 5;
    if (t < 32 && nb0 + t < N) {
        rowptr[nb0 + t] = e0 + excl[t];
        rowend[nb0 + t] = e0 + excl[t + 1];
    }
    for (int i = t; i < ecnt; i += 256) csr[e0 + i] = sorted[i];
    // ---- fused SAGE mean: 4 waves x 8 nodes; round-16: 8-deep load batch ----
    int wv = t >> 6, lane = t & 63;
    for (int k = 0; k < 8; k++) {
        int local = wv * 8 + k;
        int node = nb0 + local;
        if (node >= N) continue;
        int le0 = excl[local], le1 = excl[local + 1];
        f32x2 aA = {0.f, 0.f}, aB = {0.f, 0.f}, aC = {0.f, 0.f}, aD = {0.f, 0.f};
        int e = le0;
        for (; e + 7 < le1; e += 8) {
            int s0 = sorted[e],     s1 = sorted[e + 1], s2 = sorted[e + 2], s3 = sorted[e + 3];
            int s4 = sorted[e + 4], s5 = sorted[e + 5], s6 = sorted[e + 6], s7 = sorted[e + 7];
            unsigned int u0 = xb[(unsigned)(s0 + lane)];
            unsigned int u1 = xb[(unsigned)(s1 + lane)];
            unsigned int u2 = xb[(unsigned)(s2 + lane)];
            unsigned int u3 = xb[(unsigned)(s3 + lane)];
            unsigned int u4 = xb[(unsigned)(s4 + lane)];
            unsigned int u5 = xb[(unsigned)(s5 + lane)];
            unsigned int u6 = xb[(unsigned)(s6 + lane)];
            unsigned int u7 = xb[(unsigned)(s7 + lane)];
            pk_add(aA, bf2_to_p2(u0));
            pk_add(aB, bf2_to_p2(u1));
            pk_add(aC, bf2_to_p2(u2));
            pk_add(aD, bf2_to_p2(u3));
            pk_add(aA, bf2_to_p2(u4));
            pk_add(aB, bf2_to_p2(u5));
            pk_add(aC, bf2_to_p2(u6));
            pk_add(aD, bf2_to_p2(u7));
        }
        for (; e + 3 < le1; e += 4) {
            int s0 = sorted[e], s1 = sorted[e + 1], s2 = sorted[e + 2], s3 = sorted[e + 3];
            unsigned int u0 = xb[(unsigned)(s0 + lane)];
            unsigned int u1 = xb[(unsigned)(s1 + lane)];
            unsigned int u2 = xb[(unsigned)(s2 + lane)];
            unsigned int u3 = xb[(unsigned)(s3 + lane)];
            pk_add(aA, bf2_to_p2(u0));
            pk_add(aB, bf2_to_p2(u1));
            pk_add(aC, bf2_to_p2(u2));
            pk_add(aD, bf2_to_p2(u3));
        }
        for (; e < le1; e++)
            pk_add(aA, bf2_to_p2(xb[(unsigned)(sorted[e] + lane)]));
        pk_add(aA, aB);
        pk_add(aC, aD);
        pk_add(aA, aC);
        int dg = le1 - le0;
        float inv = 1.0f / (float)(dg > 0 ? dg : 1);
        f32x2 sm = aA; sm.x *= inv; sm.y *= inv;
        unsigned int o = packbf(sm);
        __builtin_nontemporal_store(o, meanb + (size_t)node * 64 + lane);
    }
}

// ---------------- MFMA GEMM (hb = relu([mean|x]@Bh + bs)) + fused a_s/a_d ----------------
__global__ __launch_bounds__(256) void k_mfma_h(const unsigned short* __restrict__ A0,
                                                const unsigned short* __restrict__ A1,
                                                const unsigned short* __restrict__ Bp,
                                                const float* __restrict__ bias,
                                                const float* __restrict__ wsd,
                                                unsigned short* __restrict__ outb,
                                                float* __restrict__ a_s,
                                                float* __restrict__ a_d, int M) {
    const int NC = 8;                       // NCOL = 128, K = 256
    __shared__ unsigned short sH[64][136];
    __shared__ float swsd[1056];            // [o][132] transposed+padded
    int tid = threadIdx.x;
    int wave = tid >> 6;
    int lane = tid & 63;
    int row0 = blockIdx.x * 64 + wave * 16;
    int n16 = lane & 15, quad = lane >> 4;
    int arow = row0 + n16;
    int arowc = arow < M ? arow : 0;
    for (int i = tid; i < 1056; i += 256) swsd[i] = wsd[i];
    f32x4 acc[NC];
    #pragma unroll
    for (int i = 0; i < NC; i++) acc[i] = (f32x4){0.f, 0.f, 0.f, 0.f};
    #pragma unroll
    for (int kb = 0; kb < 8; kb++) {
        const unsigned short* ap = (kb < 4)
            ? (A0 + (size_t)arowc * 128 + kb * 32 + quad * 8)
            : (A1 + (size_t)arowc * 128 + (kb - 4) * 32 + quad * 8);
        short8 af = *(const short8*)ap;
        #pragma unroll
        for (int nc = 0; nc < NC; nc++) {
            short8 bf = *(const short8*)(Bp + ((((size_t)(kb * NC + nc) * 4 + quad) * 16 + n16) << 3));
            acc[nc] = __builtin_amdgcn_mfma_f32_16x16x32_bf16(af, bf, acc[nc], 0, 0, 0);
        }
    }
    int orow = row0 + quad * 4;
    int lrow = wave * 16 + quad * 4;
    #pragma unroll
    for (int r = 0; r < 4; r++) {
        int m = orow + r;
        #pragma unroll
        for (int nc = 0; nc < NC; nc++) {
            int col = nc * 16 + n16;
            float v = fmaxf(acc[nc][r] + bias[col], 0.f);
            unsigned short bv = f2bf(v);
            sH[lrow + r][col] = bv;
            if (m < M) outb[(size_t)m * 128 + col] = bv;
        }
    }
    __syncthreads();
    // fused a_s/a_d: 64 rows x 8 outputs = 512 jobs, 2 per thread.
    #pragma unroll
    for (int j = tid; j < 512; j += 256) {
        int m = j >> 3, o = j & 7;
        const float* wr = swsd + o * 132;
        f32x2 pa = {0.f, 0.f}, pb = {0.f, 0.f};
        #pragma unroll 4
        for (int kb = 0; kb < 16; kb++) {
            const unsigned int* hp = (const unsigned int*)&sH[m][kb * 8];
            unsigned int h0 = hp[0], h1 = hp[1], h2 = hp[2], h3 = hp[3];
            f32x2 wa0 = *(const f32x2*)(wr + kb * 8);
            f32x2 wa1 = *(const f32x2*)(wr + kb * 8 + 2);
            f32x2 wb0 = *(const f32x2*)(wr + kb * 8 + 4);
            f32x2 wb1 = *(const f32x2*)(wr + kb * 8 + 6);
            pk_fma(pa, bf2_to_p2(h0), wa0);
            pk_fma(pb, bf2_to_p2(h1), wa1);
            pk_fma(pa, bf2_to_p2(h2), wb0);
            pk_fma(pb, bf2_to_p2(h3), wb1);
        }
        pk_add(pa, pb);
        float accd = pa.x + pa.y;
        int n = blockIdx.x * 64 + m;
        if (n < M) {
            if (o < 4) a_s[n * 4 + o] = accd;
            else       a_d[n * 4 + (o - 4)] = accd;
        }
    }
}

// ---------------- GAT: two-pass softmax aggregation ----------------
// round-16: pass-1 pads edge list to %8 with zero-weight row-0 entries;
// pass-2 is a pure 8-deep load/consume loop (no tail, no guards).
#define EDGE_CAP 192
__global__ __launch_bounds__(128) void k_gat_agg(const int* __restrict__ rowptr,
                                                 const int* __restrict__ rowend,
                                                 const int* __restrict__ csr,
                                                 const unsigned int* __restrict__ hb,
                                                 const float* __restrict__ a_s,
                                                 const float* __restrict__ a_d,
                                                 unsigned int* __restrict__ aggb, int N) {
    __shared__ int   sSrc[2][EDGE_CAP];
    __shared__ float sAl[2][EDGE_CAP * 4];
    int wv = threadIdx.x >> 6;
    int lane = threadIdx.x & 63;
    int n = blockIdx.x * 2 + wv;
    bool active = n < N;
    int e0 = 0, deg = 0;
    float4 ad = {0.f, 0.f, 0.f, 0.f};
    if (active) {
        e0 = rowptr[n];
        deg = rowend[n] - e0;
        ad = *(const float4*)(a_d + (size_t)n * 4);
    }
    // pass 1: per-edge weights (coalesced), partial denom in registers
    f32x4 psum = {0.f, 0.f, 0.f, 0.f};
    for (int base = 0; base < deg; base += 64) {
        int i = base + lane;
        if (i < deg) {
            int s64 = csr[e0 + i];                       // src<<6
            float4 as = *(const float4*)(a_s + (size_t)(s64 >> 4)); // src*4
            f32x4 w;
            w.x = __expf(leaky(as.x + ad.x));
            w.y = __expf(leaky(as.y + ad.y));
            w.z = __expf(leaky(as.z + ad.z));
            w.w = __expf(leaky(as.w + ad.w));
            psum += w;
            if (i < EDGE_CAP) {
                sSrc[wv][i] = s64;
                *(f32x4*)&sAl[wv][i * 4] = w;
            }
        }
    }
    #pragma unroll
    for (int o = 32; o; o >>= 1) {
        psum.x += __shfl_xor(psum.x, o);
        psum.y += __shfl_xor(psum.y, o);
        psum.z += __shfl_xor(psum.z, o);
        psum.w += __shfl_xor(psum.w, o);
    }
    f32x4 inv;
    inv.x = psum.x > 0.f ? 0.25f / psum.x : 0.f;
    inv.y = psum.y > 0.f ? 0.25f / psum.y : 0.f;
    inv.z = psum.z > 0.f ? 0.25f / psum.z : 0.f;
    inv.w = psum.w > 0.f ? 0.25f / psum.w : 0.f;
    int capdeg = deg < EDGE_CAP ? deg : EDGE_CAP;
    for (int base = 0; base < capdeg; base += 64) {
        int i = base + lane;
        if (i < capdeg) {
            f32x4 w = *(f32x4*)&sAl[wv][i * 4];
            w *= inv;
            *(f32x4*)&sAl[wv][i * 4] = w;
        }
    }
    // pad to multiple of 8 with zero-weight row-0 entries (EDGE_CAP%8==0 so
    // the pad always fits; contributes exactly 0 to the sums)
    int padded = (capdeg + 7) & ~7;
    if (lane < padded - capdeg) {
        sSrc[wv][capdeg + lane] = 0;
        *(f32x4*)&sAl[wv][(capdeg + lane) * 4] = (f32x4){0.f, 0.f, 0.f, 0.f};
    }
    // NO __syncthreads: sSrc/sAl strictly wave-local; waves drift apart
    // pass 2: pure 8-deep gather/consume (8 loads in flight, zero guards)
    f32x2 ac0 = {0.f, 0.f}, ac1 = {0.f, 0.f}, ac2 = {0.f, 0.f}, ac3 = {0.f, 0.f};
    for (int e = 0; e < padded; e += 8) {
        int4 sa = *(const int4*)&sSrc[wv][e];
        int4 sb = *(const int4*)&sSrc[wv][e + 4];
        unsigned int u0 = hb[(unsigned)(sa.x + lane)];
        unsigned int u1 = hb[(unsigned)(sa.y + lane)];
        unsigned int u2 = hb[(unsigned)(sa.z + lane)];
        unsigned int u3 = hb[(unsigned)(sa.w + lane)];
        unsigned int u4 = hb[(unsigned)(sb.x + lane)];
        unsigned int u5 = hb[(unsigned)(sb.y + lane)];
        unsigned int u6 = hb[(unsigned)(sb.z + lane)];
        unsigned int u7 = hb[(unsigned)(sb.w + lane)];
        #pragma unroll
        for (int j = 0; j < 8; j++) {
            unsigned int u = j == 0 ? u0 : j == 1 ? u1 : j == 2 ? u2 : j == 3 ? u3
                           : j == 4 ? u4 : j == 5 ? u5 : j == 6 ? u6 : u7;
            f32x4 w4 = *(const f32x4*)&sAl[wv][(e + j) * 4];
            f32x2 wa = __builtin_shufflevector(w4, w4, 0, 1);
            f32x2 wb = __builtin_shufflevector(w4, w4, 2, 3);
            f32x2 p = bf2_to_p2(u);
            pk_fma_lo(ac0, p, wa); pk_fma_hi(ac1, p, wa);
            pk_fma_lo(ac2, p, wb); pk_fma_hi(ac3, p, wb);
        }
    }
    for (int i = EDGE_CAP; i < deg; i++) {   // overflow (statistically never)
        int s64 = csr[e0 + i];
        float4 as = *(const float4*)(a_s + (size_t)(s64 >> 4));
        f32x4 w;
        w.x = __expf(leaky(as.x + ad.x)) * inv.x;
        w.y = __expf(leaky(as.y + ad.y)) * inv.y;
        w.z = __expf(leaky(as.z + ad.z)) * inv.z;
        w.w = __expf(leaky(as.w + ad.w)) * inv.w;
        f32x2 v0 = bf2_to_p2(hb[(unsigned)(s64 + lane)]);
        f32x2 wa = {w.x, w.y}, wb = {w.z, w.w};
        pk_fma_lo(ac0, v0, wa); pk_fma_hi(ac1, v0, wa);
        pk_fma_lo(ac2, v0, wb); pk_fma_hi(ac3, v0, wb);
    }
    if (!active) return;
    unsigned int* rowu = aggb + (size_t)n * 256 + lane;
    __builtin_nontemporal_store(packbf(ac0), rowu + 0);
    __builtin_nontemporal_store(packbf(ac1), rowu + 64);
    __builtin_nontemporal_store(packbf(ac2), rowu + 128);
    __builtin_nontemporal_store(packbf(ac3), rowu + 192);
}

// ---------------- fused tail: g = relu(aggb @ Bg + bg); out = g @ Bf + bl ----------------
__global__ __launch_bounds__(256) void k_mfma_tail(const unsigned short* __restrict__ aggb,
                                                   const unsigned short* __restrict__ Bg,
                                                   const float* __restrict__ bg,
                                                   const unsigned short* __restrict__ Bf,
                                                   const float* __restrict__ bl,
                                                   float* __restrict__ out, int M) {
    __shared__ unsigned short sG[64][136];   // +8-short pad -> only 2-way (free) LDS aliasing
    int wave = threadIdx.x >> 6;
    int lane = threadIdx.x & 63;
    int row0 = blockIdx.x * 64 + wave * 16;
    int n16 = lane & 15, quad = lane >> 4;
    // ---- stage 1: K=512, NCOL=128 ----
    {
        int arow = row0 + n16;
        int arowc = arow < M ? arow : 0;
        const unsigned short* ap = aggb + (size_t)arowc * 512 + quad * 8;
        f32x4 acc[8];
        #pragma unroll
        for (int i = 0; i < 8; i++) acc[i] = (f32x4){0.f, 0.f, 0.f, 0.f};
        #pragma unroll
        for (int kb = 0; kb < 16; kb++) {
            short8 af = *(const short8*)(ap + kb * 32);
            #pragma unroll
            for (int nc = 0; nc < 8; nc++) {
                short8 bf = *(const short8*)(Bg + ((((size_t)(kb * 8 + nc) * 4 + quad) * 16 + n16) << 3));
                acc[nc] = __builtin_amdgcn_mfma_f32_16x16x32_bf16(af, bf, acc[nc], 0, 0, 0);
            }
        }
        int lrow = wave * 16 + quad * 4;
        #pragma unroll
        for (int r = 0; r < 4; r++) {
            #pragma unroll
            for (int nc = 0; nc < 8; nc++) {
                int col = nc * 16 + n16;
                sG[lrow + r][col] = f2bf(fmaxf(acc[nc][r] + bg[col], 0.f));
            }
        }
    }
    __syncthreads();
    // ---- stage 2: K=128, NCOL=64 from LDS ----
    {
        f32x4 acc[4];
        #pragma unroll
        for (int i = 0; i < 4; i++) acc[i] = (f32x4){0.f, 0.f, 0.f, 0.f};
        #pragma unroll
        for (int kb = 0; kb < 4; kb++) {
            short8 af = *(const short8*)&sG[wave * 16 + n16][kb * 32 + quad * 8];
            #pragma unroll
            for (int nc = 0; nc < 4; nc++) {
                short8 bf = *(const short8*)(Bf + ((((size_t)(kb * 4 + nc) * 4 + quad) * 16 + n16) << 3));
                acc[nc] = __builtin_amdgcn_mfma_f32_16x16x32_bf16(af, bf, acc[nc], 0, 0, 0);
            }
        }
        int orow = row0 + quad * 4;
        #pragma unroll
        for (int r = 0; r < 4; r++) {
            int m = orow + r;
            if (m < M) {
                #pragma unroll
                for (int nc = 0; nc < 4; nc++) {
                    int col = nc * 16 + n16;
                    out[(size_t)m * 64 + col] = acc[nc][r] + bl[col];
                }
            }
        }
    }
}

extern "C" void kernel_launch(void* const* d_in, const int* in_sizes, int n_in,
                              void* d_out, int out_size, void* d_ws, size_t ws_size,
                              hipStream_t stream) {
    const float* x    = (const float*)d_in[0];
    const int*   ei   = (const int*)d_in[1];
    const float* Wl   = (const float*)d_in[2];
    const float* Wr   = (const float*)d_in[3];
    const float* bs   = (const float*)d_in[4];
    const float* Wsrc = (const float*)d_in[5];
    const float* Wdst = (const float*)d_in[6];
    const float* atts = (const float*)d_in[7];
    const float* attd = (const float*)d_in[8];
    const float* bg   = (const float*)d_in[9];
    const float* Wlin = (const float*)d_in[10];
    const float* bl   = (const float*)d_in[11];
    int N = in_sizes[0] / D;
    int E = in_sizes[1] / 2;
    int nbuck = (N + 31) >> 5;   // 1563 for N=50000
    int npairs = N * 64;

    char* w = (char*)d_ws;
    auto alloc = [&](size_t bytes) {
        char* p = w;
        w += (bytes + 255) & ~(size_t)255;
        return p;
    };
    unsigned int* xb     = (unsigned int*)alloc((size_t)N * 256);   // [N,128] bf16
    unsigned int* meanb  = (unsigned int*)alloc((size_t)N * 256);   // [N,128] bf16
    unsigned int* hb     = (unsigned int*)alloc((size_t)N * 256);   // [N,128] bf16
    unsigned int* aggb   = (unsigned int*)alloc((size_t)N * 1024);  // [N,512] bf16
    unsigned short* Bh   = (unsigned short*)alloc(65536 * 2);
    unsigned short* Bg   = (unsigned short*)alloc(65536 * 2);
    unsigned short* Bf   = (unsigned short*)alloc(8192 * 2);
    float* a_s           = (float*)alloc((size_t)N * 16);
    float* a_d           = (float*)alloc((size_t)N * 16);
    float* wsd           = (float*)alloc(1056 * 4);                 // [8][132] transposed
    int* rowptr          = (int*)alloc((size_t)N * 4);
    int* rowend          = (int*)alloc((size_t)N * 4);
    int* bcur            = (int*)alloc((size_t)MAXBUCK * CPAD * 4); // one 64B line per bucket
    unsigned int* ebuf   = (unsigned int*)alloc((size_t)MAXBUCK * BSLOT * 4); // bucket-padded
    int* csr             = (int*)alloc((size_t)MAXBUCK * BSLOT * 4);          // bucket-padded
    (void)ws_size; (void)n_in; (void)out_size;

    hipMemsetAsync(bcur, 0, (size_t)MAXBUCK * CPAD * 4, stream);

    int scatB = (E + CH - 1) / CH;
    int workBlocks = (PREP_CNT + npairs + 255) / 256;
    k_early<<<scatB + workBlocks, 256, 0, stream>>>(x, npairs, ei, E, nbuck, scatB,
                                                    bcur, ebuf,
                                                    Wl, Wr, Wsrc, Wlin, Wdst, atts, attd,
                                                    Bh, Bg, Bf, wsd, xb);
    k_build_sage<<<nbuck, 256, 0, stream>>>(ebuf, bcur, xb, csr, rowptr, rowend, meanb, N);

    k_mfma_h<<<(N + 63) / 64, 256, 0, stream>>>((const unsigned short*)meanb,
                                                (const unsigned short*)xb, Bh, bs, wsd,
                                                (unsigned short*)hb, a_s, a_d, N);
    k_gat_agg<<<(N + 1) / 2, 128, 0, stream>>>(rowptr, rowend, csr, hb, a_s, a_d, aggb, N);
    k_mfma_tail<<<(N + 63) / 64, 256, 0, stream>>>((const unsigned short*)aggb, Bg, bg,
                                                   Bf, bl, (float*)d_out, N);
}